// Round 9
// baseline (261.749 us; speedup 1.0000x reference)
//
#include <hip/hip_runtime.h>

#define B_TOT 65536
#define T_STEPS 10
#define D_IN 16
#define H 64
#define G4H 256
#define D_MLP 30
#define D_OUT 4
#define BTILE 32
#define PSTR 68     // h-plane row stride (shorts): 4-row stride = 8 banks -> conflict-free q-groups
#define DSTR 34     // d buffer row stride (shorts)
#define LOG2E 1.44269504088896340736f
#define TWO_LOG2E 2.88539008177792681472f

typedef short short8 __attribute__((ext_vector_type(8)));
typedef float float4_t __attribute__((ext_vector_type(4)));
typedef __bf16 bf16x8_t __attribute__((ext_vector_type(8)));

static __device__ __forceinline__ short f2bf(float f) {  // round-half-up (activations)
    unsigned u = __builtin_bit_cast(unsigned, f);
    return (short)(unsigned short)((u + 0x8000u) >> 16);
}
static __device__ __forceinline__ short f2bf_rne(float f) {  // weights
    unsigned u = __builtin_bit_cast(unsigned, f);
    unsigned r = (u + 0x7FFFu + ((u >> 16) & 1u)) >> 16;
    return (short)(unsigned short)r;
}
static __device__ __forceinline__ float bf2f(short s) {
    unsigned u = ((unsigned)(unsigned short)s) << 16;
    return __builtin_bit_cast(float, u);
}
static __device__ __forceinline__ float4_t mfma16(short8 a, short8 b, float4_t c) {
    return __builtin_amdgcn_mfma_f32_16x16x32_bf16(
        __builtin_bit_cast(bf16x8_t, a), __builtin_bit_cast(bf16x8_t, b), c, 0, 0, 0);
}
// z pre-scaled by log2e in the weights: sigmoid(z) = 1/(1+2^-z')
static __device__ __forceinline__ float sigm2(float z) {
    return __builtin_amdgcn_rcpf(1.0f + __builtin_amdgcn_exp2f(-z));
}
// z pre-scaled by 2*log2e: tanh(z) = 1 - 2/(1+2^z')
static __device__ __forceinline__ float tanh2(float z) {
    return 1.0f - 2.0f * __builtin_amdgcn_rcpf(1.0f + __builtin_amdgcn_exp2f(z));
}
static __device__ __forceinline__ float tanh_c(float x) {  // unscaled input (cell state)
    return tanh2(x * TWO_LOG2E);
}

// ---- workspace layout (bytes) ----
#define WS_WU1 0        // 48 frags x 1KB = 49152
#define WS_WU2 49152    // 48 frags = 49152
#define WS_WD  98304    // 4 frags = 4096
#define WS_BZ1 102400   // 256 f32
#define WS_B2P 103424   // 256 f32
#define WS_BDP 104448   // 32 f32

// Weights pre-swizzled to MFMA B-frag order (frag f, lane l, elem e -> B[k=(l>>4)*8+e][n=l&15])
// and pre-scaled: i/f/o gates by log2e, L1 g-gate by 2*log2e, L2 g-gate (relu) raw.
// wu1: A1=[h1(0:64)|x-reg], kt0=U1[0:32], kt1=U1[32:64], kt2=[W1(16);zeros(16)]
// wu2: A2=[d(0:32)|h2(0:64)], kt0=[W2(30);0;0], kt1=U2[0:32], kt2=U2[32:64]
// wd : d = h1 @ Wd (cols padded 30->32), unscaled
__global__ void precompute(const float* __restrict__ W1, const float* __restrict__ U1,
                           const float* __restrict__ b1, const float* __restrict__ Wd,
                           const float* __restrict__ bd, const float* __restrict__ W2,
                           const float* __restrict__ U2, const float* __restrict__ b2,
                           short* __restrict__ wu1_sw, short* __restrict__ wu2_sw,
                           short* __restrict__ wd_sw, float* __restrict__ bz1,
                           float* __restrict__ b2p, float* __restrict__ bdp) {
    const int lane = threadIdx.x;  // 64
    const int b = blockIdx.x;      // 101
    if (b < 48) {
        const int f = b, jt = f / 12, g = (f / 3) & 3, kt = f % 3;
        const int col = g * 64 + jt * 16 + (lane & 15);
        const float sc = (g == 2) ? TWO_LOG2E : LOG2E;
        for (int e = 0; e < 8; ++e) {
            const int sub = (lane >> 4) * 8 + e;  // 0..31
            float v;
            if (kt == 0)      v = U1[sub * G4H + col];
            else if (kt == 1) v = U1[(sub + 32) * G4H + col];
            else              v = (sub < 16) ? W1[sub * G4H + col] : 0.0f;
            wu1_sw[(f * 64 + lane) * 8 + e] = f2bf_rne(v * sc);
        }
    } else if (b < 96) {
        const int f = b - 48, jt = f / 12, g = (f / 3) & 3, kt = f % 3;
        const int col = g * 64 + jt * 16 + (lane & 15);
        const float sc = (g == 2) ? 1.0f : LOG2E;  // relu gate stays raw
        for (int e = 0; e < 8; ++e) {
            const int sub = (lane >> 4) * 8 + e;
            float v;
            if (kt == 0)      v = (sub < D_MLP) ? W2[sub * G4H + col] : 0.0f;
            else if (kt == 1) v = U2[sub * G4H + col];
            else              v = U2[(sub + 32) * G4H + col];
            wu2_sw[(f * 64 + lane) * 8 + e] = f2bf_rne(v * sc);
        }
    } else if (b < 100) {
        const int fd = b - 96, nt = fd >> 1, kt = fd & 1;
        const int col = nt * 16 + (lane & 15);
        for (int e = 0; e < 8; ++e) {
            const int k = kt * 32 + (lane >> 4) * 8 + e;  // h1 dim 0..63
            const float v = (col < D_MLP) ? Wd[k * D_MLP + col] : 0.0f;
            wd_sw[(fd * 64 + lane) * 8 + e] = f2bf_rne(v);
        }
    } else {
        for (int i = 0; i < 4; ++i) {
            const int c = i * 64 + lane;
            const int g = c >> 6;
            bz1[c] = b1[c] * ((g == 2) ? TWO_LOG2E : LOG2E);
            b2p[c] = b2[c] * ((g == 2) ? 1.0f : LOG2E);
        }
        if (lane < 32) bdp[lane] = (lane < D_MLP) ? bd[lane] : 0.0f;
    }
}

// ---------------- fully fused: LSTM1 -> Dense(D in LDS) -> LSTM2 -> projection ----------------
__global__ __launch_bounds__(256)
__attribute__((amdgpu_waves_per_eu(4, 8)))
void lstm_all(const float* __restrict__ x, const short* __restrict__ wu1_sw,
              const short* __restrict__ wu2_sw, const short* __restrict__ wd_sw,
              const float* __restrict__ bz1, const float* __restrict__ b2p,
              const float* __restrict__ bdp, const float* __restrict__ Wf,
              const float* __restrict__ bfin, float* __restrict__ out) {
    __shared__ __align__(16) short P[2][BTILE * PSTR];        // 8704 B h-plane (dbuf)
    __shared__ __align__(16) short D[T_STEPS][BTILE * DSTR];  // 21760 B dense buffer

    const int tid = threadIdx.x, lane = tid & 63, wave = tid >> 6;
    const int q = lane >> 4, n = lane & 15;
    const int b0 = blockIdx.x * BTILE;

    // ---- phase-1 weights: wave owns gate-col slice [g*64 + wave*16, +16) ----
    short8 wz[4][3];
    float bzv[4];
#pragma unroll
    for (int g = 0; g < 4; ++g) {
#pragma unroll
        for (int kt = 0; kt < 3; ++kt)
            wz[g][kt] = ((const short8*)wu1_sw)[(wave * 12 + g * 3 + kt) * 64 + lane];
        bzv[g] = bz1[g * 64 + wave * 16 + n];
    }
    // d-projection: wave -> (row-tile mw, col-tile ntw)
    const int mw = wave >> 1, ntw = wave & 1;
    const short8 wd0 = ((const short8*)wd_sw)[(ntw * 2 + 0) * 64 + lane];
    const short8 wd1 = ((const short8*)wd_sw)[(ntw * 2 + 1) * 64 + lane];
    const float bdv = bdp[ntw * 16 + n];

    for (int i = tid; i < BTILE * PSTR; i += 256) P[0][i] = 0;

    float4_t cc[2];
    cc[0] = (float4_t){0, 0, 0, 0};
    cc[1] = (float4_t){0, 0, 0, 0};

    // x direct-from-global A-frags, ONE PER M-TILE:
    // m=0 -> batch rows b0+n, m=1 -> batch rows b0+16+n; lane(q<2) holds k=q*8..q*8+8
    const float* xlane0 = x + (size_t)(b0 + n) * (T_STEPS * D_IN) + q * 8;
    const float* xlane1 = xlane0 + (size_t)16 * (T_STEPS * D_IN);
    float4 px[2][2];
    if (q < 2) {
        px[0][0] = *(const float4*)xlane0;
        px[0][1] = *(const float4*)(xlane0 + 4);
        px[1][0] = *(const float4*)xlane1;
        px[1][1] = *(const float4*)(xlane1 + 4);
    }
    __syncthreads();  // P[0] zeros visible

    // ================= phase 1: LSTM1 (tanh) + Dense into D =================
    for (int t = 0; t < T_STEPS; ++t) {
        const short* cb = P[t & 1];
        short* nb = P[(t & 1) ^ 1];

        short8 ax[2];
        ax[0] = (short8){0, 0, 0, 0, 0, 0, 0, 0};
        ax[1] = (short8){0, 0, 0, 0, 0, 0, 0, 0};
        if (q < 2) {
#pragma unroll
            for (int m = 0; m < 2; ++m) {
                ax[m][0] = f2bf(px[m][0].x); ax[m][1] = f2bf(px[m][0].y);
                ax[m][2] = f2bf(px[m][0].z); ax[m][3] = f2bf(px[m][0].w);
                ax[m][4] = f2bf(px[m][1].x); ax[m][5] = f2bf(px[m][1].y);
                ax[m][6] = f2bf(px[m][1].z); ax[m][7] = f2bf(px[m][1].w);
            }
            const int tn = (t + 1 < T_STEPS) ? t + 1 : T_STEPS - 1;
            px[0][0] = *(const float4*)(xlane0 + tn * D_IN);
            px[0][1] = *(const float4*)(xlane0 + tn * D_IN + 4);
            px[1][0] = *(const float4*)(xlane1 + tn * D_IN);
            px[1][1] = *(const float4*)(xlane1 + tn * D_IN + 4);
        }

#pragma unroll
        for (int m = 0; m < 2; ++m) {
            const int arow = (16 * m + n) * PSTR + q * 8;
            const short8 ah0 = *(const short8*)&cb[arow];
            const short8 ah1 = *(const short8*)&cb[arow + 32];
            float4_t ac[4];
#pragma unroll
            for (int g = 0; g < 4; ++g) {
                float4_t c = (float4_t){bzv[g], bzv[g], bzv[g], bzv[g]};
                c = mfma16(ah0, wz[g][0], c);
                c = mfma16(ah1, wz[g][1], c);
                c = mfma16(ax[m], wz[g][2], c);
                ac[g] = c;
            }
#pragma unroll
            for (int jj = 0; jj < 4; ++jj) {
                const float iv = sigm2(ac[0][jj]);
                const float fv = sigm2(ac[1][jj]);
                const float gv = tanh2(ac[2][jj]);
                const float ov = sigm2(ac[3][jj]);
                const float cn = fv * cc[m][jj] + iv * gv;
                cc[m][jj] = cn;
                nb[(16 * m + q * 4 + jj) * PSTR + wave * 16 + n] = f2bf(ov * tanh_c(cn));
            }
        }
        __syncthreads();  // h1_t complete

        // d_t = h1_t @ Wd + bd -> D[t]  (each wave: one 16x16 tile, k=64)
        {
            const int drow = (16 * mw + n) * PSTR + q * 8;
            const short8 dh0 = *(const short8*)&nb[drow];
            const short8 dh1 = *(const short8*)&nb[drow + 32];
            float4_t dd = (float4_t){bdv, bdv, bdv, bdv};
            dd = mfma16(dh0, wd0, dd);
            dd = mfma16(dh1, wd1, dd);
            short* dt = &D[t][0];
#pragma unroll
            for (int jj = 0; jj < 4; ++jj)
                dt[(16 * mw + q * 4 + jj) * DSTR + ntw * 16 + n] = f2bf(dd[jj]);
        }
    }

    // ================= phase boundary =================
    __syncthreads();  // all d-reads of P done before re-zeroing
#pragma unroll
    for (int g = 0; g < 4; ++g) {
#pragma unroll
        for (int kt = 0; kt < 3; ++kt)
            wz[g][kt] = ((const short8*)wu2_sw)[(wave * 12 + g * 3 + kt) * 64 + lane];
        bzv[g] = b2p[g * 64 + wave * 16 + n];
    }
    cc[0] = (float4_t){0, 0, 0, 0};
    cc[1] = (float4_t){0, 0, 0, 0};
    for (int i = tid; i < BTILE * PSTR; i += 256) P[0][i] = 0;
    __syncthreads();

    // ================= phase 2: LSTM2 (relu) from D =================
    for (int t = 0; t < T_STEPS; ++t) {
        const short* cb = P[t & 1];
        short* nb = P[(t & 1) ^ 1];

#pragma unroll
        for (int m = 0; m < 2; ++m) {
            const int ar = 16 * m + n;
            const short8 ad  = *(const short8*)&D[t][ar * DSTR + q * 8];
            const short8 ah0 = *(const short8*)&cb[ar * PSTR + q * 8];
            const short8 ah1 = *(const short8*)&cb[ar * PSTR + 32 + q * 8];
            float4_t ac[4];
#pragma unroll
            for (int g = 0; g < 4; ++g) {
                float4_t c = (float4_t){bzv[g], bzv[g], bzv[g], bzv[g]};
                c = mfma16(ad, wz[g][0], c);
                c = mfma16(ah0, wz[g][1], c);
                c = mfma16(ah1, wz[g][2], c);
                ac[g] = c;
            }
#pragma unroll
            for (int jj = 0; jj < 4; ++jj) {
                const float iv = sigm2(ac[0][jj]);
                const float fv = sigm2(ac[1][jj]);
                const float gv = fmaxf(ac[2][jj], 0.0f);   // raw (unscaled) gate
                const float ov = sigm2(ac[3][jj]);
                const float cn = fv * cc[m][jj] + iv * gv;
                cc[m][jj] = cn;
                nb[(16 * m + q * 4 + jj) * PSTR + wave * 16 + n] = f2bf(ov * fmaxf(cn, 0.0f));
            }
        }
        __syncthreads();
    }

    // ---- out = h2_9 @ Wf + bf ; t=9 wrote nb = P[0] ----
    if (tid < 128) {
        const int r = tid >> 2, c = tid & 3;
        float s = bfin[c];
#pragma unroll
        for (int kb = 0; kb < 8; ++kb) {
            const short8 h8 = *(const short8*)&P[0][r * PSTR + kb * 8];
#pragma unroll
            for (int e = 0; e < 8; ++e)
                s += bf2f(h8[e]) * Wf[(kb * 8 + e) * D_OUT + c];
        }
        out[(size_t)(b0 + r) * D_OUT + c] = s;
    }
}

extern "C" void kernel_launch(void* const* d_in, const int* in_sizes, int n_in,
                              void* d_out, int out_size, void* d_ws, size_t ws_size,
                              hipStream_t stream) {
    const float* x  = (const float*)d_in[0];
    const float* W1 = (const float*)d_in[1];
    const float* U1 = (const float*)d_in[2];
    const float* b1 = (const float*)d_in[3];
    const float* Wd = (const float*)d_in[4];
    const float* bd = (const float*)d_in[5];
    const float* W2 = (const float*)d_in[6];
    const float* U2 = (const float*)d_in[7];
    const float* b2 = (const float*)d_in[8];
    const float* Wf = (const float*)d_in[9];
    const float* bf = (const float*)d_in[10];
    float* out = (float*)d_out;

    char* ws = (char*)d_ws;
    short* wu1_sw = (short*)(ws + WS_WU1);
    short* wu2_sw = (short*)(ws + WS_WU2);
    short* wd_sw  = (short*)(ws + WS_WD);
    float* bz1    = (float*)(ws + WS_BZ1);
    float* b2p    = (float*)(ws + WS_B2P);
    float* bdp    = (float*)(ws + WS_BDP);

    precompute<<<101, 64, 0, stream>>>(W1, U1, b1, Wd, bd, W2, U2, b2,
                                       wu1_sw, wu2_sw, wd_sw, bz1, b2p, bdp);
    lstm_all<<<B_TOT / BTILE, 256, 0, stream>>>(x, wu1_sw, wu2_sw, wd_sw,
                                                bz1, b2p, bdp, Wf, bf, out);
}

// Round 10
// 260.928 us; speedup vs baseline: 1.0031x; 1.0031x over previous
//
#include <hip/hip_runtime.h>

#define B_TOT 65536
#define T_STEPS 10
#define D_IN 16
#define H 64
#define G4H 256
#define D_MLP 30
#define D_OUT 4
#define BTILE 32
#define PSTR 68     // h-plane row stride (shorts): 4-row stride = 8 banks -> conflict-free q-groups
#define DSTR 34     // d buffer row stride (shorts)
#define LOG2E 1.44269504088896340736f
#define TWO_LOG2E 2.88539008177792681472f

typedef short short8 __attribute__((ext_vector_type(8)));
typedef float float4_t __attribute__((ext_vector_type(4)));
typedef __bf16 bf16x8_t __attribute__((ext_vector_type(8)));

static __device__ __forceinline__ short f2bf(float f) {  // round-half-up (activations)
    unsigned u = __builtin_bit_cast(unsigned, f);
    return (short)(unsigned short)((u + 0x8000u) >> 16);
}
static __device__ __forceinline__ short f2bf_rne(float f) {  // weights
    unsigned u = __builtin_bit_cast(unsigned, f);
    unsigned r = (u + 0x7FFFu + ((u >> 16) & 1u)) >> 16;
    return (short)(unsigned short)r;
}
static __device__ __forceinline__ float bf2f(short s) {
    unsigned u = ((unsigned)(unsigned short)s) << 16;
    return __builtin_bit_cast(float, u);
}
static __device__ __forceinline__ float4_t mfma16(short8 a, short8 b, float4_t c) {
    return __builtin_amdgcn_mfma_f32_16x16x32_bf16(
        __builtin_bit_cast(bf16x8_t, a), __builtin_bit_cast(bf16x8_t, b), c, 0, 0, 0);
}
// z pre-scaled by log2e in the weights: sigmoid(z) = 1/(1+2^-z')
static __device__ __forceinline__ float sigm2(float z) {
    return __builtin_amdgcn_rcpf(1.0f + __builtin_amdgcn_exp2f(-z));
}
// z pre-scaled by 2*log2e: tanh(z) = 1 - 2/(1+2^z')
static __device__ __forceinline__ float tanh2(float z) {
    return 1.0f - 2.0f * __builtin_amdgcn_rcpf(1.0f + __builtin_amdgcn_exp2f(z));
}
static __device__ __forceinline__ float tanh_c(float x) {  // unscaled input (cell state)
    return tanh2(x * TWO_LOG2E);
}

// ---- workspace layout (bytes) ----
#define WS_WU1 0        // 48 frags x 1KB = 49152
#define WS_WU2 49152    // 48 frags = 49152
#define WS_WD  98304    // 4 frags = 4096
#define WS_BZ1 102400   // 256 f32
#define WS_B2P 103424   // 256 f32
#define WS_BDP 104448   // 32 f32

// Weights pre-swizzled to MFMA B-frag order (frag f, lane l, elem e -> B[k=(l>>4)*8+e][n=l&15])
// and pre-scaled: i/f/o gates by log2e, L1 g-gate by 2*log2e, L2 g-gate (relu) raw.
// wu1: A1=[h1(0:64)|x-reg], kt0=U1[0:32], kt1=U1[32:64], kt2=[W1(16);zeros(16)]
// wu2: A2=[d(0:32)|h2(0:64)], kt0=[W2(30);0;0], kt1=U2[0:32], kt2=U2[32:64]
// wd : d = h1 @ Wd (cols padded 30->32), unscaled
__global__ void precompute(const float* __restrict__ W1, const float* __restrict__ U1,
                           const float* __restrict__ b1, const float* __restrict__ Wd,
                           const float* __restrict__ bd, const float* __restrict__ W2,
                           const float* __restrict__ U2, const float* __restrict__ b2,
                           short* __restrict__ wu1_sw, short* __restrict__ wu2_sw,
                           short* __restrict__ wd_sw, float* __restrict__ bz1,
                           float* __restrict__ b2p, float* __restrict__ bdp) {
    const int lane = threadIdx.x;  // 64
    const int b = blockIdx.x;      // 101
    if (b < 48) {
        const int f = b, jt = f / 12, g = (f / 3) & 3, kt = f % 3;
        const int col = g * 64 + jt * 16 + (lane & 15);
        const float sc = (g == 2) ? TWO_LOG2E : LOG2E;
        for (int e = 0; e < 8; ++e) {
            const int sub = (lane >> 4) * 8 + e;  // 0..31
            float v;
            if (kt == 0)      v = U1[sub * G4H + col];
            else if (kt == 1) v = U1[(sub + 32) * G4H + col];
            else              v = (sub < 16) ? W1[sub * G4H + col] : 0.0f;
            wu1_sw[(f * 64 + lane) * 8 + e] = f2bf_rne(v * sc);
        }
    } else if (b < 96) {
        const int f = b - 48, jt = f / 12, g = (f / 3) & 3, kt = f % 3;
        const int col = g * 64 + jt * 16 + (lane & 15);
        const float sc = (g == 2) ? 1.0f : LOG2E;  // relu gate stays raw
        for (int e = 0; e < 8; ++e) {
            const int sub = (lane >> 4) * 8 + e;
            float v;
            if (kt == 0)      v = (sub < D_MLP) ? W2[sub * G4H + col] : 0.0f;
            else if (kt == 1) v = U2[sub * G4H + col];
            else              v = U2[(sub + 32) * G4H + col];
            wu2_sw[(f * 64 + lane) * 8 + e] = f2bf_rne(v * sc);
        }
    } else if (b < 100) {
        const int fd = b - 96, nt = fd >> 1, kt = fd & 1;
        const int col = nt * 16 + (lane & 15);
        for (int e = 0; e < 8; ++e) {
            const int k = kt * 32 + (lane >> 4) * 8 + e;  // h1 dim 0..63
            const float v = (col < D_MLP) ? Wd[k * D_MLP + col] : 0.0f;
            wd_sw[(fd * 64 + lane) * 8 + e] = f2bf_rne(v);
        }
    } else {
        for (int i = 0; i < 4; ++i) {
            const int c = i * 64 + lane;
            const int g = c >> 6;
            bz1[c] = b1[c] * ((g == 2) ? TWO_LOG2E : LOG2E);
            b2p[c] = b2[c] * ((g == 2) ? 1.0f : LOG2E);
        }
        if (lane < 32) bdp[lane] = (lane < D_MLP) ? bd[lane] : 0.0f;
    }
}

// ---------------- fully fused: LSTM1 -> Dense(D in LDS) -> LSTM2 -> projection ----------------
__global__ __launch_bounds__(256)
__attribute__((amdgpu_waves_per_eu(4, 4)))   // 128-reg budget: fits ~100-reg working set, no spills
void lstm_all(const float* __restrict__ x, const short* __restrict__ wu1_sw,
              const short* __restrict__ wu2_sw, const short* __restrict__ wd_sw,
              const float* __restrict__ bz1, const float* __restrict__ b2p,
              const float* __restrict__ bdp, const float* __restrict__ Wf,
              const float* __restrict__ bfin, float* __restrict__ out) {
    __shared__ __align__(16) short P[2][BTILE * PSTR];        // 8704 B h-plane (dbuf)
    __shared__ __align__(16) short D[T_STEPS][BTILE * DSTR];  // 21760 B dense buffer

    const int tid = threadIdx.x, lane = tid & 63, wave = tid >> 6;
    const int q = lane >> 4, n = lane & 15;
    const int b0 = blockIdx.x * BTILE;

    // ---- phase-1 weights: wave owns gate-col slice [g*64 + wave*16, +16) ----
    short8 wz[4][3];
    float bzv[4];
#pragma unroll
    for (int g = 0; g < 4; ++g) {
#pragma unroll
        for (int kt = 0; kt < 3; ++kt)
            wz[g][kt] = ((const short8*)wu1_sw)[(wave * 12 + g * 3 + kt) * 64 + lane];
        bzv[g] = bz1[g * 64 + wave * 16 + n];
    }
    // d-projection: wave -> (row-tile mw, col-tile ntw)
    const int mw = wave >> 1, ntw = wave & 1;
    const short8 wd0 = ((const short8*)wd_sw)[(ntw * 2 + 0) * 64 + lane];
    const short8 wd1 = ((const short8*)wd_sw)[(ntw * 2 + 1) * 64 + lane];
    const float bdv = bdp[ntw * 16 + n];

    for (int i = tid; i < BTILE * PSTR; i += 256) P[0][i] = 0;

    float4_t cc[2];
    cc[0] = (float4_t){0, 0, 0, 0};
    cc[1] = (float4_t){0, 0, 0, 0};

    // x direct-from-global A-frags, one per m-tile:
    // m=0 -> batch rows b0+n, m=1 -> batch rows b0+16+n; lane(q<2) holds k=q*8..q*8+8
    const float* xlane0 = x + (size_t)(b0 + n) * (T_STEPS * D_IN) + q * 8;
    const float* xlane1 = xlane0 + (size_t)16 * (T_STEPS * D_IN);
    float4 px[2][2];
    if (q < 2) {
        px[0][0] = *(const float4*)xlane0;
        px[0][1] = *(const float4*)(xlane0 + 4);
        px[1][0] = *(const float4*)xlane1;
        px[1][1] = *(const float4*)(xlane1 + 4);
    }
    __syncthreads();  // P[0] zeros visible

    // ================= phase 1: LSTM1 (tanh) + Dense into D =================
    for (int t = 0; t < T_STEPS; ++t) {
        const short* cb = P[t & 1];
        short* nb = P[(t & 1) ^ 1];

        short8 ax[2];
        ax[0] = (short8){0, 0, 0, 0, 0, 0, 0, 0};
        ax[1] = (short8){0, 0, 0, 0, 0, 0, 0, 0};
        if (q < 2) {
#pragma unroll
            for (int m = 0; m < 2; ++m) {
                ax[m][0] = f2bf(px[m][0].x); ax[m][1] = f2bf(px[m][0].y);
                ax[m][2] = f2bf(px[m][0].z); ax[m][3] = f2bf(px[m][0].w);
                ax[m][4] = f2bf(px[m][1].x); ax[m][5] = f2bf(px[m][1].y);
                ax[m][6] = f2bf(px[m][1].z); ax[m][7] = f2bf(px[m][1].w);
            }
            const int tn = (t + 1 < T_STEPS) ? t + 1 : T_STEPS - 1;
            px[0][0] = *(const float4*)(xlane0 + tn * D_IN);
            px[0][1] = *(const float4*)(xlane0 + tn * D_IN + 4);
            px[1][0] = *(const float4*)(xlane1 + tn * D_IN);
            px[1][1] = *(const float4*)(xlane1 + tn * D_IN + 4);
        }

#pragma unroll
        for (int m = 0; m < 2; ++m) {
            const int arow = (16 * m + n) * PSTR + q * 8;
            const short8 ah0 = *(const short8*)&cb[arow];
            const short8 ah1 = *(const short8*)&cb[arow + 32];
            float4_t ac[4];
#pragma unroll
            for (int g = 0; g < 4; ++g) {
                float4_t c = (float4_t){bzv[g], bzv[g], bzv[g], bzv[g]};
                c = mfma16(ah0, wz[g][0], c);
                c = mfma16(ah1, wz[g][1], c);
                c = mfma16(ax[m], wz[g][2], c);
                ac[g] = c;
            }
#pragma unroll
            for (int jj = 0; jj < 4; ++jj) {
                const float iv = sigm2(ac[0][jj]);
                const float fv = sigm2(ac[1][jj]);
                const float gv = tanh2(ac[2][jj]);
                const float ov = sigm2(ac[3][jj]);
                const float cn = fv * cc[m][jj] + iv * gv;
                cc[m][jj] = cn;
                nb[(16 * m + q * 4 + jj) * PSTR + wave * 16 + n] = f2bf(ov * tanh_c(cn));
            }
        }
        __syncthreads();  // h1_t complete

        // d_t = h1_t @ Wd + bd -> D[t]  (each wave: one 16x16 tile, k=64)
        {
            const int drow = (16 * mw + n) * PSTR + q * 8;
            const short8 dh0 = *(const short8*)&nb[drow];
            const short8 dh1 = *(const short8*)&nb[drow + 32];
            float4_t dd = (float4_t){bdv, bdv, bdv, bdv};
            dd = mfma16(dh0, wd0, dd);
            dd = mfma16(dh1, wd1, dd);
            short* dt = &D[t][0];
#pragma unroll
            for (int jj = 0; jj < 4; ++jj)
                dt[(16 * mw + q * 4 + jj) * DSTR + ntw * 16 + n] = f2bf(dd[jj]);
        }
    }

    // ================= phase boundary =================
    __syncthreads();  // all d-reads of P done before re-zeroing
#pragma unroll
    for (int g = 0; g < 4; ++g) {
#pragma unroll
        for (int kt = 0; kt < 3; ++kt)
            wz[g][kt] = ((const short8*)wu2_sw)[(wave * 12 + g * 3 + kt) * 64 + lane];
        bzv[g] = b2p[g * 64 + wave * 16 + n];
    }
    cc[0] = (float4_t){0, 0, 0, 0};
    cc[1] = (float4_t){0, 0, 0, 0};
    for (int i = tid; i < BTILE * PSTR; i += 256) P[0][i] = 0;
    __syncthreads();

    // ================= phase 2: LSTM2 (relu) from D =================
    for (int t = 0; t < T_STEPS; ++t) {
        const short* cb = P[t & 1];
        short* nb = P[(t & 1) ^ 1];

#pragma unroll
        for (int m = 0; m < 2; ++m) {
            const int ar = 16 * m + n;
            const short8 ad  = *(const short8*)&D[t][ar * DSTR + q * 8];
            const short8 ah0 = *(const short8*)&cb[ar * PSTR + q * 8];
            const short8 ah1 = *(const short8*)&cb[ar * PSTR + 32 + q * 8];
            float4_t ac[4];
#pragma unroll
            for (int g = 0; g < 4; ++g) {
                float4_t c = (float4_t){bzv[g], bzv[g], bzv[g], bzv[g]};
                c = mfma16(ad, wz[g][0], c);
                c = mfma16(ah0, wz[g][1], c);
                c = mfma16(ah1, wz[g][2], c);
                ac[g] = c;
            }
#pragma unroll
            for (int jj = 0; jj < 4; ++jj) {
                const float iv = sigm2(ac[0][jj]);
                const float fv = sigm2(ac[1][jj]);
                const float gv = fmaxf(ac[2][jj], 0.0f);   // raw (unscaled) gate
                const float ov = sigm2(ac[3][jj]);
                const float cn = fv * cc[m][jj] + iv * gv;
                cc[m][jj] = cn;
                nb[(16 * m + q * 4 + jj) * PSTR + wave * 16 + n] = f2bf(ov * fmaxf(cn, 0.0f));
            }
        }
        __syncthreads();
    }

    // ---- out = h2_9 @ Wf + bf ; t=9 wrote nb = P[0] ----
    if (tid < 128) {
        const int r = tid >> 2, c = tid & 3;
        float s = bfin[c];
#pragma unroll
        for (int kb = 0; kb < 8; ++kb) {
            const short8 h8 = *(const short8*)&P[0][r * PSTR + kb * 8];
#pragma unroll
            for (int e = 0; e < 8; ++e)
                s += bf2f(h8[e]) * Wf[(kb * 8 + e) * D_OUT + c];
        }
        out[(size_t)(b0 + r) * D_OUT + c] = s;
    }
}

extern "C" void kernel_launch(void* const* d_in, const int* in_sizes, int n_in,
                              void* d_out, int out_size, void* d_ws, size_t ws_size,
                              hipStream_t stream) {
    const float* x  = (const float*)d_in[0];
    const float* W1 = (const float*)d_in[1];
    const float* U1 = (const float*)d_in[2];
    const float* b1 = (const float*)d_in[3];
    const float* Wd = (const float*)d_in[4];
    const float* bd = (const float*)d_in[5];
    const float* W2 = (const float*)d_in[6];
    const float* U2 = (const float*)d_in[7];
    const float* b2 = (const float*)d_in[8];
    const float* Wf = (const float*)d_in[9];
    const float* bf = (const float*)d_in[10];
    float* out = (float*)d_out;

    char* ws = (char*)d_ws;
    short* wu1_sw = (short*)(ws + WS_WU1);
    short* wu2_sw = (short*)(ws + WS_WU2);
    short* wd_sw  = (short*)(ws + WS_WD);
    float* bz1    = (float*)(ws + WS_BZ1);
    float* b2p    = (float*)(ws + WS_B2P);
    float* bdp    = (float*)(ws + WS_BDP);

    precompute<<<101, 64, 0, stream>>>(W1, U1, b1, Wd, bd, W2, U2, b2,
                                       wu1_sw, wu2_sw, wd_sw, bz1, b2p, bdp);
    lstm_all<<<B_TOT / BTILE, 256, 0, stream>>>(x, wu1_sw, wu2_sw, wd_sw,
                                                bz1, b2p, bdp, Wf, bf, out);
}

// Round 11
// 217.564 us; speedup vs baseline: 1.2031x; 1.1993x over previous
//
#include <hip/hip_runtime.h>

#define B_TOT 65536
#define T_STEPS 10
#define D_IN 16
#define H 64
#define G4H 256
#define D_MLP 30
#define D_OUT 4
#define BTILE 32
#define PSTR 68     // h-plane row stride (shorts): 4-row stride = 8 banks -> conflict-free q-groups
#define DSTR 34     // d buffer row stride (shorts)
#define LOG2E 1.44269504088896340736f
#define TWO_LOG2E 2.88539008177792681472f

typedef short short8 __attribute__((ext_vector_type(8)));
typedef float float4_t __attribute__((ext_vector_type(4)));
typedef __bf16 bf16x8_t __attribute__((ext_vector_type(8)));

static __device__ __forceinline__ short f2bf(float f) {  // round-half-up (activations)
    unsigned u = __builtin_bit_cast(unsigned, f);
    return (short)(unsigned short)((u + 0x8000u) >> 16);
}
static __device__ __forceinline__ short f2bf_rne(float f) {  // weights
    unsigned u = __builtin_bit_cast(unsigned, f);
    unsigned r = (u + 0x7FFFu + ((u >> 16) & 1u)) >> 16;
    return (short)(unsigned short)r;
}
static __device__ __forceinline__ float bf2f(short s) {
    unsigned u = ((unsigned)(unsigned short)s) << 16;
    return __builtin_bit_cast(float, u);
}
static __device__ __forceinline__ float4_t mfma16(short8 a, short8 b, float4_t c) {
    return __builtin_amdgcn_mfma_f32_16x16x32_bf16(
        __builtin_bit_cast(bf16x8_t, a), __builtin_bit_cast(bf16x8_t, b), c, 0, 0, 0);
}
// z pre-scaled by log2e in the weights: sigmoid(z) = 1/(1+2^-z')
static __device__ __forceinline__ float sigm2(float z) {
    return __builtin_amdgcn_rcpf(1.0f + __builtin_amdgcn_exp2f(-z));
}
// z pre-scaled by 2*log2e: tanh(z) = 1 - 2/(1+2^z')
static __device__ __forceinline__ float tanh2(float z) {
    return 1.0f - 2.0f * __builtin_amdgcn_rcpf(1.0f + __builtin_amdgcn_exp2f(z));
}
static __device__ __forceinline__ float tanh_c(float x) {  // unscaled input (cell state)
    return tanh2(x * TWO_LOG2E);
}

// ---- workspace layout (bytes) ----
#define WS_WU1 0        // 48 frags x 1KB = 49152
#define WS_WU2 49152    // 48 frags = 49152
#define WS_WD  98304    // 4 frags = 4096
#define WS_BZ1 102400   // 256 f32
#define WS_B2P 103424   // 256 f32
#define WS_BDP 104448   // 32 f32

// Weights pre-swizzled to MFMA B-frag order (frag f, lane l, elem e -> B[k=(l>>4)*8+e][n=l&15])
// and pre-scaled: i/f/o gates by log2e, L1 g-gate by 2*log2e, L2 g-gate (relu) raw.
// wu1: A1=[h1(0:64)|x-reg], kt0=U1[0:32], kt1=U1[32:64], kt2=[W1(16);zeros(16)]
// wu2: A2=[d(0:32)|h2(0:64)], kt0=[W2(30);0;0], kt1=U2[0:32], kt2=U2[32:64]
// wd : d = h1 @ Wd (cols padded 30->32), unscaled
__global__ void precompute(const float* __restrict__ W1, const float* __restrict__ U1,
                           const float* __restrict__ b1, const float* __restrict__ Wd,
                           const float* __restrict__ bd, const float* __restrict__ W2,
                           const float* __restrict__ U2, const float* __restrict__ b2,
                           short* __restrict__ wu1_sw, short* __restrict__ wu2_sw,
                           short* __restrict__ wd_sw, float* __restrict__ bz1,
                           float* __restrict__ b2p, float* __restrict__ bdp) {
    const int lane = threadIdx.x;  // 64
    const int b = blockIdx.x;      // 101
    if (b < 48) {
        const int f = b, jt = f / 12, g = (f / 3) & 3, kt = f % 3;
        const int col = g * 64 + jt * 16 + (lane & 15);
        const float sc = (g == 2) ? TWO_LOG2E : LOG2E;
        for (int e = 0; e < 8; ++e) {
            const int sub = (lane >> 4) * 8 + e;  // 0..31
            float v;
            if (kt == 0)      v = U1[sub * G4H + col];
            else if (kt == 1) v = U1[(sub + 32) * G4H + col];
            else              v = (sub < 16) ? W1[sub * G4H + col] : 0.0f;
            wu1_sw[(f * 64 + lane) * 8 + e] = f2bf_rne(v * sc);
        }
    } else if (b < 96) {
        const int f = b - 48, jt = f / 12, g = (f / 3) & 3, kt = f % 3;
        const int col = g * 64 + jt * 16 + (lane & 15);
        const float sc = (g == 2) ? 1.0f : LOG2E;  // relu gate stays raw
        for (int e = 0; e < 8; ++e) {
            const int sub = (lane >> 4) * 8 + e;
            float v;
            if (kt == 0)      v = (sub < D_MLP) ? W2[sub * G4H + col] : 0.0f;
            else if (kt == 1) v = U2[sub * G4H + col];
            else              v = U2[(sub + 32) * G4H + col];
            wu2_sw[(f * 64 + lane) * 8 + e] = f2bf_rne(v * sc);
        }
    } else if (b < 100) {
        const int fd = b - 96, nt = fd >> 1, kt = fd & 1;
        const int col = nt * 16 + (lane & 15);
        for (int e = 0; e < 8; ++e) {
            const int k = kt * 32 + (lane >> 4) * 8 + e;  // h1 dim 0..63
            const float v = (col < D_MLP) ? Wd[k * D_MLP + col] : 0.0f;
            wd_sw[(fd * 64 + lane) * 8 + e] = f2bf_rne(v);
        }
    } else {
        for (int i = 0; i < 4; ++i) {
            const int c = i * 64 + lane;
            const int g = c >> 6;
            bz1[c] = b1[c] * ((g == 2) ? TWO_LOG2E : LOG2E);
            b2p[c] = b2[c] * ((g == 2) ? 1.0f : LOG2E);
        }
        if (lane < 32) bdp[lane] = (lane < D_MLP) ? bd[lane] : 0.0f;
    }
}

// ---------------- fully fused: LSTM1 -> Dense(D in LDS) -> LSTM2 -> projection ----------------
__global__ __launch_bounds__(256)
__attribute__((amdgpu_waves_per_eu(3, 4)))   // min=3 -> 170-reg budget: proven no-spill point (R7)
void lstm_all(const float* __restrict__ x, const short* __restrict__ wu1_sw,
              const short* __restrict__ wu2_sw, const short* __restrict__ wd_sw,
              const float* __restrict__ bz1, const float* __restrict__ b2p,
              const float* __restrict__ bdp, const float* __restrict__ Wf,
              const float* __restrict__ bfin, float* __restrict__ out) {
    __shared__ __align__(16) short P[2][BTILE * PSTR];        // 8704 B h-plane (dbuf)
    __shared__ __align__(16) short D[T_STEPS][BTILE * DSTR];  // 21760 B dense buffer

    const int tid = threadIdx.x, lane = tid & 63, wave = tid >> 6;
    const int q = lane >> 4, n = lane & 15;
    const int b0 = blockIdx.x * BTILE;

    // ---- phase-1 weights: wave owns gate-col slice [g*64 + wave*16, +16) ----
    short8 wz[4][3];
    float bzv[4];
#pragma unroll
    for (int g = 0; g < 4; ++g) {
#pragma unroll
        for (int kt = 0; kt < 3; ++kt)
            wz[g][kt] = ((const short8*)wu1_sw)[(wave * 12 + g * 3 + kt) * 64 + lane];
        bzv[g] = bz1[g * 64 + wave * 16 + n];
    }
    // d-projection: wave -> (row-tile mw, col-tile ntw)
    const int mw = wave >> 1, ntw = wave & 1;
    const short8 wd0 = ((const short8*)wd_sw)[(ntw * 2 + 0) * 64 + lane];
    const short8 wd1 = ((const short8*)wd_sw)[(ntw * 2 + 1) * 64 + lane];
    const float bdv = bdp[ntw * 16 + n];

    for (int i = tid; i < BTILE * PSTR; i += 256) P[0][i] = 0;

    float4_t cc[2];
    cc[0] = (float4_t){0, 0, 0, 0};
    cc[1] = (float4_t){0, 0, 0, 0};

    // x direct-from-global A-frags, one per m-tile:
    // m=0 -> batch rows b0+n, m=1 -> batch rows b0+16+n; lane(q<2) holds k=q*8..q*8+8
    const float* xlane0 = x + (size_t)(b0 + n) * (T_STEPS * D_IN) + q * 8;
    const float* xlane1 = xlane0 + (size_t)16 * (T_STEPS * D_IN);
    float4 px[2][2];
    if (q < 2) {
        px[0][0] = *(const float4*)xlane0;
        px[0][1] = *(const float4*)(xlane0 + 4);
        px[1][0] = *(const float4*)xlane1;
        px[1][1] = *(const float4*)(xlane1 + 4);
    }
    __syncthreads();  // P[0] zeros visible

    // ================= phase 1: LSTM1 (tanh) + Dense into D =================
    for (int t = 0; t < T_STEPS; ++t) {
        const short* cb = P[t & 1];
        short* nb = P[(t & 1) ^ 1];

        short8 ax[2];
        ax[0] = (short8){0, 0, 0, 0, 0, 0, 0, 0};
        ax[1] = (short8){0, 0, 0, 0, 0, 0, 0, 0};
        if (q < 2) {
#pragma unroll
            for (int m = 0; m < 2; ++m) {
                ax[m][0] = f2bf(px[m][0].x); ax[m][1] = f2bf(px[m][0].y);
                ax[m][2] = f2bf(px[m][0].z); ax[m][3] = f2bf(px[m][0].w);
                ax[m][4] = f2bf(px[m][1].x); ax[m][5] = f2bf(px[m][1].y);
                ax[m][6] = f2bf(px[m][1].z); ax[m][7] = f2bf(px[m][1].w);
            }
            const int tn = (t + 1 < T_STEPS) ? t + 1 : T_STEPS - 1;
            px[0][0] = *(const float4*)(xlane0 + tn * D_IN);
            px[0][1] = *(const float4*)(xlane0 + tn * D_IN + 4);
            px[1][0] = *(const float4*)(xlane1 + tn * D_IN);
            px[1][1] = *(const float4*)(xlane1 + tn * D_IN + 4);
        }

#pragma unroll
        for (int m = 0; m < 2; ++m) {
            const int arow = (16 * m + n) * PSTR + q * 8;
            const short8 ah0 = *(const short8*)&cb[arow];
            const short8 ah1 = *(const short8*)&cb[arow + 32];
            float4_t ac[4];
#pragma unroll
            for (int g = 0; g < 4; ++g) {
                float4_t c = (float4_t){bzv[g], bzv[g], bzv[g], bzv[g]};
                c = mfma16(ah0, wz[g][0], c);
                c = mfma16(ah1, wz[g][1], c);
                c = mfma16(ax[m], wz[g][2], c);
                ac[g] = c;
            }
#pragma unroll
            for (int jj = 0; jj < 4; ++jj) {
                const float iv = sigm2(ac[0][jj]);
                const float fv = sigm2(ac[1][jj]);
                const float gv = tanh2(ac[2][jj]);
                const float ov = sigm2(ac[3][jj]);
                const float cn = fv * cc[m][jj] + iv * gv;
                cc[m][jj] = cn;
                nb[(16 * m + q * 4 + jj) * PSTR + wave * 16 + n] = f2bf(ov * tanh_c(cn));
            }
        }
        __syncthreads();  // h1_t complete

        // d_t = h1_t @ Wd + bd -> D[t]  (each wave: one 16x16 tile, k=64)
        {
            const int drow = (16 * mw + n) * PSTR + q * 8;
            const short8 dh0 = *(const short8*)&nb[drow];
            const short8 dh1 = *(const short8*)&nb[drow + 32];
            float4_t dd = (float4_t){bdv, bdv, bdv, bdv};
            dd = mfma16(dh0, wd0, dd);
            dd = mfma16(dh1, wd1, dd);
            short* dt = &D[t][0];
#pragma unroll
            for (int jj = 0; jj < 4; ++jj)
                dt[(16 * mw + q * 4 + jj) * DSTR + ntw * 16 + n] = f2bf(dd[jj]);
        }
    }

    // ================= phase boundary =================
    __syncthreads();  // all d-reads of P done before re-zeroing
#pragma unroll
    for (int g = 0; g < 4; ++g) {
#pragma unroll
        for (int kt = 0; kt < 3; ++kt)
            wz[g][kt] = ((const short8*)wu2_sw)[(wave * 12 + g * 3 + kt) * 64 + lane];
        bzv[g] = b2p[g * 64 + wave * 16 + n];
    }
    cc[0] = (float4_t){0, 0, 0, 0};
    cc[1] = (float4_t){0, 0, 0, 0};
    for (int i = tid; i < BTILE * PSTR; i += 256) P[0][i] = 0;
    __syncthreads();

    // ================= phase 2: LSTM2 (relu) from D =================
    for (int t = 0; t < T_STEPS; ++t) {
        const short* cb = P[t & 1];
        short* nb = P[(t & 1) ^ 1];

#pragma unroll
        for (int m = 0; m < 2; ++m) {
            const int ar = 16 * m + n;
            const short8 ad  = *(const short8*)&D[t][ar * DSTR + q * 8];
            const short8 ah0 = *(const short8*)&cb[ar * PSTR + q * 8];
            const short8 ah1 = *(const short8*)&cb[ar * PSTR + 32 + q * 8];
            float4_t ac[4];
#pragma unroll
            for (int g = 0; g < 4; ++g) {
                float4_t c = (float4_t){bzv[g], bzv[g], bzv[g], bzv[g]};
                c = mfma16(ad, wz[g][0], c);
                c = mfma16(ah0, wz[g][1], c);
                c = mfma16(ah1, wz[g][2], c);
                ac[g] = c;
            }
#pragma unroll
            for (int jj = 0; jj < 4; ++jj) {
                const float iv = sigm2(ac[0][jj]);
                const float fv = sigm2(ac[1][jj]);
                const float gv = fmaxf(ac[2][jj], 0.0f);   // raw (unscaled) gate
                const float ov = sigm2(ac[3][jj]);
                const float cn = fv * cc[m][jj] + iv * gv;
                cc[m][jj] = cn;
                nb[(16 * m + q * 4 + jj) * PSTR + wave * 16 + n] = f2bf(ov * fmaxf(cn, 0.0f));
            }
        }
        __syncthreads();
    }

    // ---- out = h2_9 @ Wf + bf ; t=9 wrote nb = P[0] ----
    if (tid < 128) {
        const int r = tid >> 2, c = tid & 3;
        float s = bfin[c];
#pragma unroll
        for (int kb = 0; kb < 8; ++kb) {
            const short8 h8 = *(const short8*)&P[0][r * PSTR + kb * 8];
#pragma unroll
            for (int e = 0; e < 8; ++e)
                s += bf2f(h8[e]) * Wf[(kb * 8 + e) * D_OUT + c];
        }
        out[(size_t)(b0 + r) * D_OUT + c] = s;
    }
}

extern "C" void kernel_launch(void* const* d_in, const int* in_sizes, int n_in,
                              void* d_out, int out_size, void* d_ws, size_t ws_size,
                              hipStream_t stream) {
    const float* x  = (const float*)d_in[0];
    const float* W1 = (const float*)d_in[1];
    const float* U1 = (const float*)d_in[2];
    const float* b1 = (const float*)d_in[3];
    const float* Wd = (const float*)d_in[4];
    const float* bd = (const float*)d_in[5];
    const float* W2 = (const float*)d_in[6];
    const float* U2 = (const float*)d_in[7];
    const float* b2 = (const float*)d_in[8];
    const float* Wf = (const float*)d_in[9];
    const float* bf = (const float*)d_in[10];
    float* out = (float*)d_out;

    char* ws = (char*)d_ws;
    short* wu1_sw = (short*)(ws + WS_WU1);
    short* wu2_sw = (short*)(ws + WS_WU2);
    short* wd_sw  = (short*)(ws + WS_WD);
    float* bz1    = (float*)(ws + WS_BZ1);
    float* b2p    = (float*)(ws + WS_B2P);
    float* bdp    = (float*)(ws + WS_BDP);

    precompute<<<101, 64, 0, stream>>>(W1, U1, b1, Wd, bd, W2, U2, b2,
                                       wu1_sw, wu2_sw, wd_sw, bz1, b2p, bdp);
    lstm_all<<<B_TOT / BTILE, 256, 0, stream>>>(x, wu1_sw, wu2_sw, wd_sw,
                                                bz1, b2p, bdp, Wf, bf, out);
}

// Round 12
// 191.546 us; speedup vs baseline: 1.3665x; 1.1358x over previous
//
#include <hip/hip_runtime.h>

#define B_TOT 65536
#define T_STEPS 10
#define D_IN 16
#define H 64
#define G4H 256
#define D_MLP 30
#define D_OUT 4
#define BTILE 32
#define PSTR 72     // h-plane row stride (shorts): 144B rows -> ds_read_b128 ALIGNED; 36dw -> 2-way only
#define DSTR 32     // d buffer row stride (shorts): 64B rows -> aligned + contiguous ad reads
#define LOG2E 1.44269504088896340736f
#define TWO_LOG2E 2.88539008177792681472f

typedef short short8 __attribute__((ext_vector_type(8)));
typedef float float4_t __attribute__((ext_vector_type(4)));
typedef __bf16 bf16x8_t __attribute__((ext_vector_type(8)));

static __device__ __forceinline__ short f2bf(float f) {  // round-half-up (activations)
    unsigned u = __builtin_bit_cast(unsigned, f);
    return (short)(unsigned short)((u + 0x8000u) >> 16);
}
static __device__ __forceinline__ short f2bf_rne(float f) {  // weights
    unsigned u = __builtin_bit_cast(unsigned, f);
    unsigned r = (u + 0x7FFFu + ((u >> 16) & 1u)) >> 16;
    return (short)(unsigned short)r;
}
static __device__ __forceinline__ float bf2f(short s) {
    unsigned u = ((unsigned)(unsigned short)s) << 16;
    return __builtin_bit_cast(float, u);
}
static __device__ __forceinline__ float4_t mfma16(short8 a, short8 b, float4_t c) {
    return __builtin_amdgcn_mfma_f32_16x16x32_bf16(
        __builtin_bit_cast(bf16x8_t, a), __builtin_bit_cast(bf16x8_t, b), c, 0, 0, 0);
}
// z pre-scaled by log2e in the weights: sigmoid(z) = 1/(1+2^-z')
static __device__ __forceinline__ float sigm2(float z) {
    return __builtin_amdgcn_rcpf(1.0f + __builtin_amdgcn_exp2f(-z));
}
// z pre-scaled by 2*log2e: tanh(z) = 1 - 2/(1+2^z')
static __device__ __forceinline__ float tanh2(float z) {
    return 1.0f - 2.0f * __builtin_amdgcn_rcpf(1.0f + __builtin_amdgcn_exp2f(z));
}
static __device__ __forceinline__ float tanh_c(float x) {  // unscaled input (cell state)
    return tanh2(x * TWO_LOG2E);
}

// ---- workspace layout (bytes) ----
#define WS_WU1 0        // 48 frags x 1KB = 49152
#define WS_WU2 49152    // 48 frags = 49152
#define WS_WD  98304    // 4 frags = 4096
#define WS_BZ1 102400   // 256 f32
#define WS_B2P 103424   // 256 f32
#define WS_BDP 104448   // 32 f32

// Weights pre-swizzled to MFMA B-frag order (frag f, lane l, elem e -> B[k=(l>>4)*8+e][n=l&15])
// and pre-scaled: i/f/o gates by log2e, L1 g-gate by 2*log2e, L2 g-gate (relu) raw.
// wu1: A1=[h1(0:64)|x-reg], kt0=U1[0:32], kt1=U1[32:64], kt2=[W1(16);zeros(16)]
// wu2: A2=[d(0:32)|h2(0:64)], kt0=[W2(30);0;0], kt1=U2[0:32], kt2=U2[32:64]
// wd : d = h1 @ Wd (cols padded 30->32), unscaled
__global__ void precompute(const float* __restrict__ W1, const float* __restrict__ U1,
                           const float* __restrict__ b1, const float* __restrict__ Wd,
                           const float* __restrict__ bd, const float* __restrict__ W2,
                           const float* __restrict__ U2, const float* __restrict__ b2,
                           short* __restrict__ wu1_sw, short* __restrict__ wu2_sw,
                           short* __restrict__ wd_sw, float* __restrict__ bz1,
                           float* __restrict__ b2p, float* __restrict__ bdp) {
    const int lane = threadIdx.x;  // 64
    const int b = blockIdx.x;      // 101
    if (b < 48) {
        const int f = b, jt = f / 12, g = (f / 3) & 3, kt = f % 3;
        const int col = g * 64 + jt * 16 + (lane & 15);
        const float sc = (g == 2) ? TWO_LOG2E : LOG2E;
        for (int e = 0; e < 8; ++e) {
            const int sub = (lane >> 4) * 8 + e;  // 0..31
            float v;
            if (kt == 0)      v = U1[sub * G4H + col];
            else if (kt == 1) v = U1[(sub + 32) * G4H + col];
            else              v = (sub < 16) ? W1[sub * G4H + col] : 0.0f;
            wu1_sw[(f * 64 + lane) * 8 + e] = f2bf_rne(v * sc);
        }
    } else if (b < 96) {
        const int f = b - 48, jt = f / 12, g = (f / 3) & 3, kt = f % 3;
        const int col = g * 64 + jt * 16 + (lane & 15);
        const float sc = (g == 2) ? 1.0f : LOG2E;  // relu gate stays raw
        for (int e = 0; e < 8; ++e) {
            const int sub = (lane >> 4) * 8 + e;
            float v;
            if (kt == 0)      v = (sub < D_MLP) ? W2[sub * G4H + col] : 0.0f;
            else if (kt == 1) v = U2[sub * G4H + col];
            else              v = U2[(sub + 32) * G4H + col];
            wu2_sw[(f * 64 + lane) * 8 + e] = f2bf_rne(v * sc);
        }
    } else if (b < 100) {
        const int fd = b - 96, nt = fd >> 1, kt = fd & 1;
        const int col = nt * 16 + (lane & 15);
        for (int e = 0; e < 8; ++e) {
            const int k = kt * 32 + (lane >> 4) * 8 + e;  // h1 dim 0..63
            const float v = (col < D_MLP) ? Wd[k * D_MLP + col] : 0.0f;
            wd_sw[(fd * 64 + lane) * 8 + e] = f2bf_rne(v);
        }
    } else {
        for (int i = 0; i < 4; ++i) {
            const int c = i * 64 + lane;
            const int g = c >> 6;
            bz1[c] = b1[c] * ((g == 2) ? TWO_LOG2E : LOG2E);
            b2p[c] = b2[c] * ((g == 2) ? 1.0f : LOG2E);
        }
        if (lane < 32) bdp[lane] = (lane < D_MLP) ? bd[lane] : 0.0f;
    }
}

// ---------------- fully fused: LSTM1 -> Dense(D in LDS) -> LSTM2 -> projection ----------------
__global__ __launch_bounds__(256)
__attribute__((amdgpu_waves_per_eu(3, 4)))   // min=3 -> 170-reg budget: proven no-spill point
void lstm_all(const float* __restrict__ x, const short* __restrict__ wu1_sw,
              const short* __restrict__ wu2_sw, const short* __restrict__ wd_sw,
              const float* __restrict__ bz1, const float* __restrict__ b2p,
              const float* __restrict__ bdp, const float* __restrict__ Wf,
              const float* __restrict__ bfin, float* __restrict__ out) {
    __shared__ __align__(16) short P[2][BTILE * PSTR];        // 9216 B h-plane (dbuf)
    __shared__ __align__(16) short D[T_STEPS][BTILE * DSTR];  // 20480 B dense buffer
    // total 29696 B -> 5 blocks/CU

    const int tid = threadIdx.x, lane = tid & 63, wave = tid >> 6;
    const int q = lane >> 4, n = lane & 15;
    const int b0 = blockIdx.x * BTILE;

    // ---- phase-1 weights: wave owns gate-col slice [g*64 + wave*16, +16) ----
    short8 wz[4][3];
    float bzv[4];
#pragma unroll
    for (int g = 0; g < 4; ++g) {
#pragma unroll
        for (int kt = 0; kt < 3; ++kt)
            wz[g][kt] = ((const short8*)wu1_sw)[(wave * 12 + g * 3 + kt) * 64 + lane];
        bzv[g] = bz1[g * 64 + wave * 16 + n];
    }
    // d-projection: wave -> (row-tile mw, col-tile ntw)
    const int mw = wave >> 1, ntw = wave & 1;
    const short8 wd0 = ((const short8*)wd_sw)[(ntw * 2 + 0) * 64 + lane];
    const short8 wd1 = ((const short8*)wd_sw)[(ntw * 2 + 1) * 64 + lane];
    const float bdv = bdp[ntw * 16 + n];

    for (int i = tid; i < BTILE * PSTR; i += 256) P[0][i] = 0;

    float4_t cc[2];
    cc[0] = (float4_t){0, 0, 0, 0};
    cc[1] = (float4_t){0, 0, 0, 0};

    // x direct-from-global A-frags, one per m-tile:
    // m=0 -> batch rows b0+n, m=1 -> batch rows b0+16+n; lane(q<2) holds k=q*8..q*8+8
    const float* xlane0 = x + (size_t)(b0 + n) * (T_STEPS * D_IN) + q * 8;
    const float* xlane1 = xlane0 + (size_t)16 * (T_STEPS * D_IN);
    float4 px[2][2];
    if (q < 2) {
        px[0][0] = *(const float4*)xlane0;
        px[0][1] = *(const float4*)(xlane0 + 4);
        px[1][0] = *(const float4*)xlane1;
        px[1][1] = *(const float4*)(xlane1 + 4);
    }
    __syncthreads();  // P[0] zeros visible

    // ================= phase 1: LSTM1 (tanh) + Dense into D =================
    for (int t = 0; t < T_STEPS; ++t) {
        const short* cb = P[t & 1];
        short* nb = P[(t & 1) ^ 1];

        short8 ax[2];
        ax[0] = (short8){0, 0, 0, 0, 0, 0, 0, 0};
        ax[1] = (short8){0, 0, 0, 0, 0, 0, 0, 0};
        if (q < 2) {
#pragma unroll
            for (int m = 0; m < 2; ++m) {
                ax[m][0] = f2bf(px[m][0].x); ax[m][1] = f2bf(px[m][0].y);
                ax[m][2] = f2bf(px[m][0].z); ax[m][3] = f2bf(px[m][0].w);
                ax[m][4] = f2bf(px[m][1].x); ax[m][5] = f2bf(px[m][1].y);
                ax[m][6] = f2bf(px[m][1].z); ax[m][7] = f2bf(px[m][1].w);
            }
            const int tn = (t + 1 < T_STEPS) ? t + 1 : T_STEPS - 1;
            px[0][0] = *(const float4*)(xlane0 + tn * D_IN);
            px[0][1] = *(const float4*)(xlane0 + tn * D_IN + 4);
            px[1][0] = *(const float4*)(xlane1 + tn * D_IN);
            px[1][1] = *(const float4*)(xlane1 + tn * D_IN + 4);
        }

#pragma unroll
        for (int m = 0; m < 2; ++m) {
            const int arow = (16 * m + n) * PSTR + q * 8;
            const short8 ah0 = *(const short8*)&cb[arow];
            const short8 ah1 = *(const short8*)&cb[arow + 32];
            float4_t ac[4];
#pragma unroll
            for (int g = 0; g < 4; ++g) {
                float4_t c = (float4_t){bzv[g], bzv[g], bzv[g], bzv[g]};
                c = mfma16(ah0, wz[g][0], c);
                c = mfma16(ah1, wz[g][1], c);
                c = mfma16(ax[m], wz[g][2], c);
                ac[g] = c;
            }
#pragma unroll
            for (int jj = 0; jj < 4; ++jj) {
                const float iv = sigm2(ac[0][jj]);
                const float fv = sigm2(ac[1][jj]);
                const float gv = tanh2(ac[2][jj]);
                const float ov = sigm2(ac[3][jj]);
                const float cn = fv * cc[m][jj] + iv * gv;
                cc[m][jj] = cn;
                nb[(16 * m + q * 4 + jj) * PSTR + wave * 16 + n] = f2bf(ov * tanh_c(cn));
            }
        }
        __syncthreads();  // h1_t complete

        // d_t = h1_t @ Wd + bd -> D[t]  (each wave: one 16x16 tile, k=64)
        {
            const int drow = (16 * mw + n) * PSTR + q * 8;
            const short8 dh0 = *(const short8*)&nb[drow];
            const short8 dh1 = *(const short8*)&nb[drow + 32];
            float4_t dd = (float4_t){bdv, bdv, bdv, bdv};
            dd = mfma16(dh0, wd0, dd);
            dd = mfma16(dh1, wd1, dd);
            short* dt = &D[t][0];
#pragma unroll
            for (int jj = 0; jj < 4; ++jj)
                dt[(16 * mw + q * 4 + jj) * DSTR + ntw * 16 + n] = f2bf(dd[jj]);
        }
    }

    // ================= phase boundary =================
    __syncthreads();  // all d-reads of P done before re-zeroing
#pragma unroll
    for (int g = 0; g < 4; ++g) {
#pragma unroll
        for (int kt = 0; kt < 3; ++kt)
            wz[g][kt] = ((const short8*)wu2_sw)[(wave * 12 + g * 3 + kt) * 64 + lane];
        bzv[g] = b2p[g * 64 + wave * 16 + n];
    }
    cc[0] = (float4_t){0, 0, 0, 0};
    cc[1] = (float4_t){0, 0, 0, 0};
    for (int i = tid; i < BTILE * PSTR; i += 256) P[0][i] = 0;
    __syncthreads();

    // ================= phase 2: LSTM2 (relu) from D =================
    for (int t = 0; t < T_STEPS; ++t) {
        const short* cb = P[t & 1];
        short* nb = P[(t & 1) ^ 1];

#pragma unroll
        for (int m = 0; m < 2; ++m) {
            const int ar = 16 * m + n;
            const short8 ad  = *(const short8*)&D[t][ar * DSTR + q * 8];
            const short8 ah0 = *(const short8*)&cb[ar * PSTR + q * 8];
            const short8 ah1 = *(const short8*)&cb[ar * PSTR + 32 + q * 8];
            float4_t ac[4];
#pragma unroll
            for (int g = 0; g < 4; ++g) {
                float4_t c = (float4_t){bzv[g], bzv[g], bzv[g], bzv[g]};
                c = mfma16(ad, wz[g][0], c);
                c = mfma16(ah0, wz[g][1], c);
                c = mfma16(ah1, wz[g][2], c);
                ac[g] = c;
            }
#pragma unroll
            for (int jj = 0; jj < 4; ++jj) {
                const float iv = sigm2(ac[0][jj]);
                const float fv = sigm2(ac[1][jj]);
                const float gv = fmaxf(ac[2][jj], 0.0f);   // raw (unscaled) gate
                const float ov = sigm2(ac[3][jj]);
                const float cn = fv * cc[m][jj] + iv * gv;
                cc[m][jj] = cn;
                nb[(16 * m + q * 4 + jj) * PSTR + wave * 16 + n] = f2bf(ov * fmaxf(cn, 0.0f));
            }
        }
        __syncthreads();
    }

    // ---- out = h2_9 @ Wf + bf ; t=9 wrote nb = P[0] ----
    if (tid < 128) {
        const int r = tid >> 2, c = tid & 3;
        float s = bfin[c];
#pragma unroll
        for (int kb = 0; kb < 8; ++kb) {
            const short8 h8 = *(const short8*)&P[0][r * PSTR + kb * 8];
#pragma unroll
            for (int e = 0; e < 8; ++e)
                s += bf2f(h8[e]) * Wf[(kb * 8 + e) * D_OUT + c];
        }
        out[(size_t)(b0 + r) * D_OUT + c] = s;
    }
}

extern "C" void kernel_launch(void* const* d_in, const int* in_sizes, int n_in,
                              void* d_out, int out_size, void* d_ws, size_t ws_size,
                              hipStream_t stream) {
    const float* x  = (const float*)d_in[0];
    const float* W1 = (const float*)d_in[1];
    const float* U1 = (const float*)d_in[2];
    const float* b1 = (const float*)d_in[3];
    const float* Wd = (const float*)d_in[4];
    const float* bd = (const float*)d_in[5];
    const float* W2 = (const float*)d_in[6];
    const float* U2 = (const float*)d_in[7];
    const float* b2 = (const float*)d_in[8];
    const float* Wf = (const float*)d_in[9];
    const float* bf = (const float*)d_in[10];
    float* out = (float*)d_out;

    char* ws = (char*)d_ws;
    short* wu1_sw = (short*)(ws + WS_WU1);
    short* wu2_sw = (short*)(ws + WS_WU2);
    short* wd_sw  = (short*)(ws + WS_WD);
    float* bz1    = (float*)(ws + WS_BZ1);
    float* b2p    = (float*)(ws + WS_B2P);
    float* bdp    = (float*)(ws + WS_BDP);

    precompute<<<101, 64, 0, stream>>>(W1, U1, b1, Wd, bd, W2, U2, b2,
                                       wu1_sw, wu2_sw, wd_sw, bz1, b2p, bdp);
    lstm_all<<<B_TOT / BTILE, 256, 0, stream>>>(x, wu1_sw, wu2_sw, wd_sw,
                                                bz1, b2p, bdp, Wf, bf, out);
}